// Round 6
// baseline (272.581 us; speedup 1.0000x reference)
//
#include <hip/hip_runtime.h>
#include <hip/hip_bf16.h>

#define SEQLEN 2048
#define NHEADS 8
#define HD 64
#define EMB 512
#define NB 2
#define ST 72   // padded LDS stride in bf16 units (144 B = 9 x 16B -> full bank spread)
#define ZST 66  // merge-buffer stride (132 B) -> 4-row groups land on distinct banks

typedef __attribute__((ext_vector_type(8))) short bf16x8;
typedef __attribute__((ext_vector_type(4))) float f32x4;

#define SCALE 0.04419417382415922f
#define NEGS  (-4.4194173824159216e18f)   // -1e20 * SCALE (faithful masked score)

__device__ __forceinline__ ushort f2b(float f) {
    __hip_bfloat16 h = __float2bfloat16(f);
    return *reinterpret_cast<ushort*>(&h);
}
__device__ __forceinline__ float b2f(ushort u) {
    unsigned int v = ((unsigned int)u) << 16;
    return __builtin_bit_cast(float, v);
}
__device__ __forceinline__ uint4 pack8(float4 a, float4 b) {
    union { ushort u[8]; uint4 v; } r;
    r.u[0] = f2b(a.x); r.u[1] = f2b(a.y); r.u[2] = f2b(a.z); r.u[3] = f2b(a.w);
    r.u[4] = f2b(b.x); r.u[5] = f2b(b.y); r.u[6] = f2b(b.z); r.u[7] = f2b(b.w);
    return r.v;
}

// ---------------- Kernel 1: per-head QKV projections via MFMA ----------------
// grid (NB*S/64, H, 3). out[s,o] = b[o] + sum_j x[s, h*64+j] * W[o,j]
// mat 0 -> Qh [n,h,s,d], mat 1 -> Kh [n,h,s,d], mat 2 -> VT [n,h,d,s] (transposed)
__global__ __launch_bounds__(256, 4) void proj_mfma(
    const float* __restrict__ q, const float* __restrict__ k, const float* __restrict__ v,
    const float* __restrict__ Wq, const float* __restrict__ bq,
    const float* __restrict__ Wk, const float* __restrict__ bk,
    const float* __restrict__ Wv, const float* __restrict__ bv,
    ushort* __restrict__ Qh, ushort* __restrict__ Kh, ushort* __restrict__ VT)
{
    const int mat = blockIdx.z;
    const float* x; const float* W; const float* b;
    switch (mat) {
      case 0:  x = q; W = Wq; b = bq; break;
      case 1:  x = k; W = Wk; b = bk; break;
      default: x = v; W = Wv; b = bv; break;
    }
    __shared__ alignas(16) ushort At[64 * ST];
    __shared__ alignas(16) ushort Bt[64 * ST];
    __shared__ alignas(16) ushort Ct[64 * ST];

    const int tid = threadIdx.x;
    const int w = tid >> 6, l = tid & 63;
    const int l15 = l & 15, l16 = l >> 4;
    const int h  = blockIdx.y;
    const int m0 = blockIdx.x * 64;          // row in [0, NB*SEQLEN)
    const int n  = m0 / SEQLEN;
    const int s0 = m0 - n * SEQLEN;
    const int wm = (w >> 1) * 32, wn = (w & 1) * 32;
    const int r8 = tid >> 3, ch8 = (tid & 7) * 8;

    {   // stage A (x tile) and B (W) as bf16
        const float* xr0 = x + (size_t)(m0 + r8) * EMB + h * HD + ch8;
        const float* xr1 = x + (size_t)(m0 + r8 + 32) * EMB + h * HD + ch8;
        float4 a0 = *(const float4*)xr0, a1 = *(const float4*)(xr0 + 4);
        float4 a2 = *(const float4*)xr1, a3 = *(const float4*)(xr1 + 4);
        const float* wr0 = W + r8 * HD + ch8;
        const float* wr1 = W + (r8 + 32) * HD + ch8;
        float4 b0 = *(const float4*)wr0, b1 = *(const float4*)(wr0 + 4);
        float4 b2 = *(const float4*)wr1, b3 = *(const float4*)(wr1 + 4);
        *(uint4*)&At[r8 * ST + ch8]        = pack8(a0, a1);
        *(uint4*)&At[(r8 + 32) * ST + ch8] = pack8(a2, a3);
        *(uint4*)&Bt[r8 * ST + ch8]        = pack8(b0, b1);
        *(uint4*)&Bt[(r8 + 32) * ST + ch8] = pack8(b2, b3);
    }
    __syncthreads();

    f32x4 acc[2][2];
    #pragma unroll
    for (int i = 0; i < 2; ++i)
        #pragma unroll
        for (int j = 0; j < 2; ++j) acc[i][j] = (f32x4){0.f, 0.f, 0.f, 0.f};

    #pragma unroll
    for (int ks = 0; ks < 2; ++ks) {
        const int ko = ks * 32 + l16 * 8;
        bf16x8 af[2], bf[2];
        #pragma unroll
        for (int i = 0; i < 2; ++i) {
            af[i] = *(const bf16x8*)&At[(wm + i * 16 + l15) * ST + ko];
            bf[i] = *(const bf16x8*)&Bt[(wn + i * 16 + l15) * ST + ko];
        }
        #pragma unroll
        for (int i = 0; i < 2; ++i)
            #pragma unroll
            for (int j = 0; j < 2; ++j)
                acc[i][j] = __builtin_amdgcn_mfma_f32_16x16x32_bf16(af[i], bf[j], acc[i][j], 0, 0, 0);
    }

    // bias + store C tile to LDS (transposed for V)
    float bb[2];
    #pragma unroll
    for (int j = 0; j < 2; ++j) bb[j] = b[wn + j * 16 + l15];
    #pragma unroll
    for (int i = 0; i < 2; ++i)
        #pragma unroll
        for (int j = 0; j < 2; ++j)
            #pragma unroll
            for (int r = 0; r < 4; ++r) {
                const int srow = wm + i * 16 + l16 * 4 + r;
                const int dcol = wn + j * 16 + l15;
                const ushort val = f2b(acc[i][j][r] + bb[j]);
                if (mat < 2) Ct[srow * ST + dcol] = val;
                else         Ct[dcol * ST + srow] = val;
            }
    __syncthreads();

    const size_t hb = ((size_t)(n * NHEADS + h)) * SEQLEN * HD;
    if (mat < 2) {
        ushort* dst = (mat == 0 ? Qh : Kh);
        *(uint4*)(dst + hb + (size_t)(s0 + r8) * HD + ch8)      = *(uint4*)&Ct[r8 * ST + ch8];
        *(uint4*)(dst + hb + (size_t)(s0 + r8 + 32) * HD + ch8) = *(uint4*)&Ct[(r8 + 32) * ST + ch8];
    } else {
        *(uint4*)(VT + hb + (size_t)r8 * SEQLEN + s0 + ch8)        = *(uint4*)&Ct[r8 * ST + ch8];
        *(uint4*)(VT + hb + (size_t)(r8 + 32) * SEQLEN + s0 + ch8) = *(uint4*)&Ct[(r8 + 32) * ST + ch8];
    }
}

// ---------------- Kernel 1c: f32 -> bf16 bulk convert (E, Wo) ----------------
__global__ __launch_bounds__(256) void econv_kernel(
    const float* __restrict__ E, ushort* __restrict__ Eb)
{
    const int i = (blockIdx.x * 256 + threadIdx.x) * 4;
    float4 f = *(const float4*)(E + i);
    ushort4 u;
    u.x = f2b(f.x); u.y = f2b(f.y); u.z = f2b(f.z); u.w = f2b(f.w);
    *(ushort4*)(Eb + i) = u;
}

// ---------------- Kernel 1d: column sums of V (for uniform row S-1) ----------
__global__ __launch_bounds__(256) void vsum_kernel(
    const ushort* __restrict__ VT, float* __restrict__ vsumG)
{
    const int nh = blockIdx.x;               // (n*NHEADS+h)
    const int tid = threadIdx.x;
    const int d = tid >> 2, part = tid & 3;
    const ushort* p = VT + (size_t)nh * SEQLEN * HD + (size_t)d * SEQLEN + part * 512;
    float s = 0.f;
    for (int i = 0; i < 64; ++i) {
        uint4 u = *(const uint4*)(p + i * 8);
        const ushort* pu = (const ushort*)&u;
        #pragma unroll
        for (int j = 0; j < 8; ++j) s += b2f(pu[j]);
    }
    __shared__ float red[64][4];
    red[d][part] = s;
    __syncthreads();
    if (tid < 64)
        vsumG[nh * HD + tid] = red[tid][0] + red[tid][1] + red[tid][2] + red[tid][3];
}

// ---------------- Kernel 2: barrier-free MFMA flash attention ----------------
// grid (S/16, H, N), 4 waves; wave w owns c-tiles t = w, w+4, ... (parity split).
// Per-wave flash state; 4 partials merged in LDS at the end.
__global__ __launch_bounds__(256, 4) void attn_mfma(
    const ushort* __restrict__ Qh, const ushort* __restrict__ Kh,
    const ushort* __restrict__ VT, const ushort* __restrict__ Eb,
    const float* __restrict__ vsumG, ushort* __restrict__ Z)
{
    const int q0 = blockIdx.x * 16;
    const int h = blockIdx.y, n = blockIdx.z;
    const int tid = threadIdx.x;
    const int w = tid >> 6, l = tid & 63;
    const int l15 = l & 15, l16 = l >> 4;

    __shared__ alignas(16) ushort Wt[4][16 * ST];     // per-wave weight tile
    __shared__ alignas(16) ushort zpL[4][16 * ZST];   // merge buffers (bf16)
    __shared__ alignas(16) ushort zrL[4][16 * ZST];
    __shared__ float mL[4][16], lL[4][16];

    const size_t hb = ((size_t)(n * NHEADS + h)) * SEQLEN * HD;

    bf16x8 qa[2];
    {
        const ushort* qp = Qh + hb + (size_t)(q0 + l15) * HD + l16 * 8;
        qa[0] = *(const bf16x8*)(qp);
        qa[1] = *(const bf16x8*)(qp + 32);
    }

    f32x4 zp[4], zr[4];
    #pragma unroll
    for (int nb = 0; nb < 4; ++nb) {
        zp[nb] = (f32x4){0.f, 0.f, 0.f, 0.f};
        zr[nb] = (f32x4){0.f, 0.f, 0.f, 0.f};
    }
    float mrow[4], lrow[4];
    #pragma unroll
    for (int r = 0; r < 4; ++r) { mrow[r] = NEGS; lrow[r] = 0.f; }

    for (int t = w; t < 32; t += 4) {
        const int c0 = t * 64;
        const bool hasP = (c0 + 63 > q0);
        const bool hasR = (c0 <= q0);

        // ---------- P (softmax) part ----------
        if (hasP) {
            bf16x8 kb[2][4];
            #pragma unroll
            for (int ks = 0; ks < 2; ++ks)
                #pragma unroll
                for (int nb = 0; nb < 4; ++nb)
                    kb[ks][nb] = *(const bf16x8*)(Kh + hb + (size_t)(c0 + nb * 16 + l15) * HD + ks * 32 + l16 * 8);
            f32x4 sc[4];
            #pragma unroll
            for (int nb = 0; nb < 4; ++nb) sc[nb] = (f32x4){0.f, 0.f, 0.f, 0.f};
            #pragma unroll
            for (int ks = 0; ks < 2; ++ks)
                #pragma unroll
                for (int nb = 0; nb < 4; ++nb)
                    sc[nb] = __builtin_amdgcn_mfma_f32_16x16x32_bf16(qa[ks], kb[ks][nb], sc[nb], 0, 0, 0);

            // prefetch V fragments (hide latency under softmax VALU)
            bf16x8 vb[2][4];
            #pragma unroll
            for (int ks = 0; ks < 2; ++ks)
                #pragma unroll
                for (int nb = 0; nb < 4; ++nb)
                    vb[ks][nb] = *(const bf16x8*)(VT + hb + (size_t)(nb * 16 + l15) * SEQLEN + c0 + ks * 32 + l16 * 8);

            float sv[4][4], mt[4], frs[4];
            #pragma unroll
            for (int r = 0; r < 4; ++r) mt[r] = NEGS;
            #pragma unroll
            for (int nb = 0; nb < 4; ++nb)
                #pragma unroll
                for (int r = 0; r < 4; ++r) {
                    float s = sc[nb][r] * SCALE;
                    if (c0 + nb * 16 + l15 <= q0 + l16 * 4 + r) s = NEGS;  // causal-ish mask (no-op on pure-P tiles)
                    sv[nb][r] = s;
                    mt[r] = fmaxf(mt[r], s);
                }
            #pragma unroll
            for (int r = 0; r < 4; ++r) {
                #pragma unroll
                for (int off = 1; off < 16; off <<= 1)
                    mt[r] = fmaxf(mt[r], __shfl_xor(mt[r], off, 64));
                const float mn = fmaxf(mrow[r], mt[r]);
                frs[r] = __expf(mrow[r] - mn);
                mrow[r] = mn;
                lrow[r] *= frs[r];
            }
            float se[4] = {0.f, 0.f, 0.f, 0.f};
            #pragma unroll
            for (int nb = 0; nb < 4; ++nb)
                #pragma unroll
                for (int r = 0; r < 4; ++r) {
                    const float e = __expf(sv[nb][r] - mrow[r]);
                    se[r] += e;
                    Wt[w][(l16 * 4 + r) * ST + nb * 16 + l15] = f2b(e);
                }
            #pragma unroll
            for (int r = 0; r < 4; ++r) {
                #pragma unroll
                for (int off = 1; off < 16; off <<= 1)
                    se[r] += __shfl_xor(se[r], off, 64);
                lrow[r] += se[r];
            }
            #pragma unroll
            for (int nb = 0; nb < 4; ++nb)
                #pragma unroll
                for (int r = 0; r < 4; ++r) zp[nb][r] *= frs[r];
            #pragma unroll
            for (int ks = 0; ks < 2; ++ks) {
                bf16x8 wa = *(const bf16x8*)&Wt[w][l15 * ST + ks * 32 + l16 * 8];
                #pragma unroll
                for (int nb = 0; nb < 4; ++nb)
                    zp[nb] = __builtin_amdgcn_mfma_f32_16x16x32_bf16(wa, vb[ks][nb], zp[nb], 0, 0, 0);
            }
        }

        // ---------- rel (Srel) part ----------
        if (hasR) {
            const int jmin = SEQLEN - 16 - q0 + c0;
            f32x4 qe[5];
            #pragma unroll
            for (int jb = 0; jb < 5; ++jb) qe[jb] = (f32x4){0.f, 0.f, 0.f, 0.f};
            #pragma unroll
            for (int ks = 0; ks < 2; ++ks)
                #pragma unroll
                for (int jb = 0; jb < 5; ++jb) {
                    const int j = jmin + jb * 16 + l15;
                    bf16x8 eb;
                    if (j < SEQLEN) eb = *(const bf16x8*)(Eb + (size_t)j * HD + ks * 32 + l16 * 8);
                    else            eb = (bf16x8){0, 0, 0, 0, 0, 0, 0, 0};
                    qe[jb] = __builtin_amdgcn_mfma_f32_16x16x32_bf16(qa[ks], eb, qe[jb], 0, 0, 0);
                }
            bf16x8 vb[2][4];
            #pragma unroll
            for (int ks = 0; ks < 2; ++ks)
                #pragma unroll
                for (int nb = 0; nb < 4; ++nb)
                    vb[ks][nb] = *(const bf16x8*)(VT + hb + (size_t)(nb * 16 + l15) * SEQLEN + c0 + ks * 32 + l16 * 8);
            // scatter skewed: (q, jloc) -> cloc = jloc + rowloc - 15
            #pragma unroll
            for (int jb = 0; jb < 5; ++jb)
                #pragma unroll
                for (int r = 0; r < 4; ++r) {
                    const int rowloc = l16 * 4 + r;
                    const int cloc = jb * 16 + l15 + rowloc - 15;
                    if (cloc >= 0 && cloc < 64) {
                        const bool msk = (c0 + cloc <= q0 + rowloc);
                        Wt[w][rowloc * ST + cloc] = f2b(msk ? qe[jb][r] : 0.f);
                    }
                }
            #pragma unroll
            for (int ks = 0; ks < 2; ++ks) {
                bf16x8 wa = *(const bf16x8*)&Wt[w][l15 * ST + ks * 32 + l16 * 8];
                #pragma unroll
                for (int nb = 0; nb < 4; ++nb)
                    zr[nb] = __builtin_amdgcn_mfma_f32_16x16x32_bf16(wa, vb[ks][nb], zr[nb], 0, 0, 0);
            }
        }
    }

    // ---------- partial writeout ----------
    #pragma unroll
    for (int nb = 0; nb < 4; ++nb)
        #pragma unroll
        for (int r = 0; r < 4; ++r) {
            const int row = l16 * 4 + r;
            zpL[w][row * ZST + nb * 16 + l15] = f2b(zp[nb][r]);
            zrL[w][row * ZST + nb * 16 + l15] = f2b(zr[nb][r]);
        }
    if (l15 == 0) {
        #pragma unroll
        for (int r = 0; r < 4; ++r) {
            mL[w][l16 * 4 + r] = mrow[r];
            lL[w][l16 * 4 + r] = lrow[r];
        }
    }
    __syncthreads();

    // ---------- merge 4 wave-partials ----------
    const int d = tid & 63, g = tid >> 6;
    #pragma unroll
    for (int i = 0; i < 4; ++i) {
        const int row = g * 4 + i;
        const float M = fmaxf(fmaxf(mL[0][row], mL[1][row]), fmaxf(mL[2][row], mL[3][row]));
        float ew[4], L = 0.f;
        #pragma unroll
        for (int w2 = 0; w2 < 4; ++w2) {
            ew[w2] = __expf(mL[w2][row] - M);
            L += lL[w2][row] * ew[w2];
        }
        float zps = 0.f, zrs = 0.f;
        #pragma unroll
        for (int w2 = 0; w2 < 4; ++w2) {
            zps += b2f(zpL[w2][row * ZST + d]) * ew[w2];
            zrs += b2f(zrL[w2][row * ZST + d]);
        }
        float z = zps / L + zrs;
        if (q0 + row == SEQLEN - 1)
            z = vsumG[(n * NHEADS + h) * HD + d] * (1.f / (float)SEQLEN) + zrs;
        Z[((size_t)(n * SEQLEN + q0 + row)) * EMB + h * HD + d] = f2b(z);
    }
}

// ---------------- Kernel 3: output projection via MFMA ----------------
__global__ __launch_bounds__(256, 4) void oproj_mfma(
    const ushort* __restrict__ Zb, const ushort* __restrict__ Wob,
    const float* __restrict__ bo, float* __restrict__ out)
{
    __shared__ alignas(16) ushort At[64 * ST];
    __shared__ alignas(16) ushort Bt[64 * ST];
    const int tid = threadIdx.x;
    const int w = tid >> 6, l = tid & 63;
    const int l15 = l & 15, l16 = l >> 4;
    const int m0 = blockIdx.x * 64;
    const int n0 = blockIdx.y * 64;
    const int wm = (w >> 1) * 32, wn = (w & 1) * 32;
    const int r8 = tid >> 3, ch8 = (tid & 7) * 8;

    f32x4 acc[2][2];
    #pragma unroll
    for (int i = 0; i < 2; ++i)
        #pragma unroll
        for (int j = 0; j < 2; ++j) acc[i][j] = (f32x4){0.f, 0.f, 0.f, 0.f};

    for (int kt = 0; kt < 8; ++kt) {
        const int k0 = kt * 64;
        __syncthreads();
        {
            uint4 a0 = *(const uint4*)(Zb  + (size_t)(m0 + r8) * EMB + k0 + ch8);
            uint4 a1 = *(const uint4*)(Zb  + (size_t)(m0 + r8 + 32) * EMB + k0 + ch8);
            uint4 b0 = *(const uint4*)(Wob + (size_t)(n0 + r8) * EMB + k0 + ch8);
            uint4 b1 = *(const uint4*)(Wob + (size_t)(n0 + r8 + 32) * EMB + k0 + ch8);
            *(uint4*)&At[r8 * ST + ch8] = a0;
            *(uint4*)&At[(r8 + 32) * ST + ch8] = a1;
            *(uint4*)&Bt[r8 * ST + ch8] = b0;
            *(uint4*)&Bt[(r8 + 32) * ST + ch8] = b1;
        }
        __syncthreads();
        #pragma unroll
        for (int ks = 0; ks < 2; ++ks) {
            const int ko = ks * 32 + l16 * 8;
            bf16x8 af[2], bf[2];
            #pragma unroll
            for (int i = 0; i < 2; ++i) {
                af[i] = *(const bf16x8*)&At[(wm + i * 16 + l15) * ST + ko];
                bf[i] = *(const bf16x8*)&Bt[(wn + i * 16 + l15) * ST + ko];
            }
            #pragma unroll
            for (int i = 0; i < 2; ++i)
                #pragma unroll
                for (int j = 0; j < 2; ++j)
                    acc[i][j] = __builtin_amdgcn_mfma_f32_16x16x32_bf16(af[i], bf[j], acc[i][j], 0, 0, 0);
        }
    }

    #pragma unroll
    for (int i = 0; i < 2; ++i)
        #pragma unroll
        for (int j = 0; j < 2; ++j) {
            const int o = n0 + wn + j * 16 + l15;
            const float bb = bo[o];
            #pragma unroll
            for (int r = 0; r < 4; ++r) {
                const int t = m0 + wm + i * 16 + l16 * 4 + r;
                out[(size_t)t * EMB + o] = acc[i][j][r] + bb;
            }
        }
}

extern "C" void kernel_launch(void* const* d_in, const int* in_sizes, int n_in,
                              void* d_out, int out_size, void* d_ws, size_t ws_size,
                              hipStream_t stream) {
    const float* v  = (const float*)d_in[0];
    const float* k  = (const float*)d_in[1];
    const float* q  = (const float*)d_in[2];
    const float* Wv = (const float*)d_in[3];
    const float* bv = (const float*)d_in[4];
    const float* Wk = (const float*)d_in[5];
    const float* bk = (const float*)d_in[6];
    const float* Wq = (const float*)d_in[7];
    const float* bq = (const float*)d_in[8];
    const float* E  = (const float*)d_in[9];
    const float* Wo = (const float*)d_in[10];
    const float* bo = (const float*)d_in[11];
    float* out = (float*)d_out;

    ushort* wsu = (ushort*)d_ws;
    const size_t perE = (size_t)NB * NHEADS * SEQLEN * HD;     // 2,097,152
    ushort* Qh  = wsu;
    ushort* Kh  = wsu + perE;
    ushort* VT  = wsu + 2 * perE;
    ushort* Eb  = wsu + 3 * perE;                              // 131072
    ushort* Wob = wsu + 3 * perE + 131072;                     // 262144
    ushort* Zb  = wsu + 3 * perE + 131072 + 262144;            // 2,097,152
    float*  vsumG = (float*)(Zb + perE);                       // 1024 f32

    dim3 gp(NB * SEQLEN / 64, NHEADS, 3);
    proj_mfma<<<gp, 256, 0, stream>>>(q, k, v, Wq, bq, Wk, bk, Wv, bv, Qh, Kh, VT);

    econv_kernel<<<SEQLEN * HD / (256 * 4), 256, 0, stream>>>(E, Eb);
    econv_kernel<<<EMB * EMB / (256 * 4), 256, 0, stream>>>(Wo, Wob);

    vsum_kernel<<<NB * NHEADS, 256, 0, stream>>>(VT, vsumG);

    dim3 g2(SEQLEN / 16, NHEADS, NB);
    attn_mfma<<<g2, 256, 0, stream>>>(Qh, Kh, VT, Eb, vsumG, Zb);

    dim3 g3(NB * SEQLEN / 64, EMB / 64);
    oproj_mfma<<<g3, 256, 0, stream>>>(Zb, Wob, bo, out);
}

// Round 8
// 249.512 us; speedup vs baseline: 1.0925x; 1.0925x over previous
//
#include <hip/hip_runtime.h>
#include <hip/hip_bf16.h>

#define SEQLEN 2048
#define NHEADS 8
#define HD 64
#define EMB 512
#define NB 2
#define ST 72   // padded LDS stride in bf16 units
#define ZST 66  // merge-buffer stride

typedef __attribute__((ext_vector_type(8))) short bf16x8;
typedef __attribute__((ext_vector_type(4))) float f32x4;

#define SCALE 0.04419417382415922f
#define NEGS  (-4.4194173824159216e18f)   // -1e20 * SCALE (faithful masked score)

__device__ __forceinline__ ushort f2b(float f) {
    __hip_bfloat16 h = __float2bfloat16(f);
    return *reinterpret_cast<ushort*>(&h);
}
__device__ __forceinline__ float b2f(ushort u) {
    unsigned int v = ((unsigned int)u) << 16;
    return __builtin_bit_cast(float, v);
}
__device__ __forceinline__ uint4 pack8(float4 a, float4 b) {
    union { ushort u[8]; uint4 v; } r;
    r.u[0] = f2b(a.x); r.u[1] = f2b(a.y); r.u[2] = f2b(a.z); r.u[3] = f2b(a.w);
    r.u[4] = f2b(b.x); r.u[5] = f2b(b.y); r.u[6] = f2b(b.z); r.u[7] = f2b(b.w);
    return r.v;
}

// ---------------- Kernel 1: per-head QKV projections via MFMA ----------------
__global__ __launch_bounds__(256, 4) void proj_mfma(
    const float* __restrict__ q, const float* __restrict__ k, const float* __restrict__ v,
    const float* __restrict__ Wq, const float* __restrict__ bq,
    const float* __restrict__ Wk, const float* __restrict__ bk,
    const float* __restrict__ Wv, const float* __restrict__ bv,
    ushort* __restrict__ Qh, ushort* __restrict__ Kh, ushort* __restrict__ VT)
{
    const int mat = blockIdx.z;
    const float* x; const float* W; const float* b;
    switch (mat) {
      case 0:  x = q; W = Wq; b = bq; break;
      case 1:  x = k; W = Wk; b = bk; break;
      default: x = v; W = Wv; b = bv; break;
    }
    __shared__ alignas(16) ushort At[64 * ST];
    __shared__ alignas(16) ushort Bt[64 * ST];
    __shared__ alignas(16) ushort Ct[64 * ST];

    const int tid = threadIdx.x;
    const int w = tid >> 6, l = tid & 63;
    const int l15 = l & 15, l16 = l >> 4;
    const int h  = blockIdx.y;
    const int m0 = blockIdx.x * 64;
    const int n  = m0 / SEQLEN;
    const int s0 = m0 - n * SEQLEN;
    const int wm = (w >> 1) * 32, wn = (w & 1) * 32;
    const int r8 = tid >> 3, ch8 = (tid & 7) * 8;

    {
        const float* xr0 = x + (size_t)(m0 + r8) * EMB + h * HD + ch8;
        const float* xr1 = x + (size_t)(m0 + r8 + 32) * EMB + h * HD + ch8;
        float4 a0 = *(const float4*)xr0, a1 = *(const float4*)(xr0 + 4);
        float4 a2 = *(const float4*)xr1, a3 = *(const float4*)(xr1 + 4);
        const float* wr0 = W + r8 * HD + ch8;
        const float* wr1 = W + (r8 + 32) * HD + ch8;
        float4 b0 = *(const float4*)wr0, b1 = *(const float4*)(wr0 + 4);
        float4 b2 = *(const float4*)wr1, b3 = *(const float4*)(wr1 + 4);
        *(uint4*)&At[r8 * ST + ch8]        = pack8(a0, a1);
        *(uint4*)&At[(r8 + 32) * ST + ch8] = pack8(a2, a3);
        *(uint4*)&Bt[r8 * ST + ch8]        = pack8(b0, b1);
        *(uint4*)&Bt[(r8 + 32) * ST + ch8] = pack8(b2, b3);
    }
    __syncthreads();

    f32x4 acc[2][2];
    #pragma unroll
    for (int i = 0; i < 2; ++i)
        #pragma unroll
        for (int j = 0; j < 2; ++j) acc[i][j] = (f32x4){0.f, 0.f, 0.f, 0.f};

    #pragma unroll
    for (int ks = 0; ks < 2; ++ks) {
        const int ko = ks * 32 + l16 * 8;
        bf16x8 af[2], bf[2];
        #pragma unroll
        for (int i = 0; i < 2; ++i) {
            af[i] = *(const bf16x8*)&At[(wm + i * 16 + l15) * ST + ko];
            bf[i] = *(const bf16x8*)&Bt[(wn + i * 16 + l15) * ST + ko];
        }
        #pragma unroll
        for (int i = 0; i < 2; ++i)
            #pragma unroll
            for (int j = 0; j < 2; ++j)
                acc[i][j] = __builtin_amdgcn_mfma_f32_16x16x32_bf16(af[i], bf[j], acc[i][j], 0, 0, 0);
    }

    float bb[2];
    #pragma unroll
    for (int j = 0; j < 2; ++j) bb[j] = b[wn + j * 16 + l15];
    #pragma unroll
    for (int i = 0; i < 2; ++i)
        #pragma unroll
        for (int j = 0; j < 2; ++j)
            #pragma unroll
            for (int r = 0; r < 4; ++r) {
                const int srow = wm + i * 16 + l16 * 4 + r;
                const int dcol = wn + j * 16 + l15;
                const ushort val = f2b(acc[i][j][r] + bb[j]);
                if (mat < 2) Ct[srow * ST + dcol] = val;
                else         Ct[dcol * ST + srow] = val;
            }
    __syncthreads();

    const size_t hb = ((size_t)(n * NHEADS + h)) * SEQLEN * HD;
    if (mat < 2) {
        ushort* dst = (mat == 0 ? Qh : Kh);
        *(uint4*)(dst + hb + (size_t)(s0 + r8) * HD + ch8)      = *(uint4*)&Ct[r8 * ST + ch8];
        *(uint4*)(dst + hb + (size_t)(s0 + r8 + 32) * HD + ch8) = *(uint4*)&Ct[(r8 + 32) * ST + ch8];
    } else {
        *(uint4*)(VT + hb + (size_t)r8 * SEQLEN + s0 + ch8)        = *(uint4*)&Ct[r8 * ST + ch8];
        *(uint4*)(VT + hb + (size_t)(r8 + 32) * SEQLEN + s0 + ch8) = *(uint4*)&Ct[(r8 + 32) * ST + ch8];
    }
}

// ---------------- Kernel 1c: f32 -> bf16 bulk convert (E then Wo, fused) ----
__global__ __launch_bounds__(256) void econv2_kernel(
    const float* __restrict__ E, ushort* __restrict__ Eb,
    const float* __restrict__ Wo, ushort* __restrict__ Wob)
{
    int idx = blockIdx.x * 256 + threadIdx.x;
    const int nE = SEQLEN * HD / 4;
    const float* src; ushort* dst;
    if (idx < nE) { src = E; dst = Eb; }
    else { idx -= nE; src = Wo; dst = Wob; }
    const int i = idx * 4;
    float4 f = *(const float4*)(src + i);
    ushort4 u;
    u.x = f2b(f.x); u.y = f2b(f.y); u.z = f2b(f.z); u.w = f2b(f.w);
    *(ushort4*)(dst + i) = u;
}

// ---------------- Kernel 1d: column sums of V (for uniform row S-1) ----------
__global__ __launch_bounds__(256) void vsum_kernel(
    const ushort* __restrict__ VT, float* __restrict__ vsumG)
{
    const int nh = blockIdx.x;
    const int tid = threadIdx.x;
    const int d = tid >> 2, part = tid & 3;
    const ushort* p = VT + (size_t)nh * SEQLEN * HD + (size_t)d * SEQLEN + part * 512;
    float s = 0.f;
    for (int i = 0; i < 64; ++i) {
        uint4 u = *(const uint4*)(p + i * 8);
        const ushort* pu = (const ushort*)&u;
        #pragma unroll
        for (int j = 0; j < 8; ++j) s += b2f(pu[j]);
    }
    __shared__ float red[64][4];
    red[d][part] = s;
    __syncthreads();
    if (tid < 64)
        vsumG[nh * HD + tid] = red[tid][0] + red[tid][1] + red[tid][2] + red[tid][3];
}

// ---------------- Kernel 2: MFMA flash attention, 2 row-groups x 2 c-parities -
// grid (S/32, H, N), 4 waves. Wave w = (wr = w>>1, wc = w&1): rows qw = q0+16*wr,
// c-tiles t = wc, wc+2, ... Fragments direct from global (no staging, no in-loop
// barriers); per-wave flash state merged pairwise (c-parity) in LDS at the end.
__global__ __launch_bounds__(256, 4) void attn_mfma(
    const ushort* __restrict__ Qh, const ushort* __restrict__ Kh,
    const ushort* __restrict__ VT, const ushort* __restrict__ Eb,
    const float* __restrict__ vsumG, ushort* __restrict__ Z)
{
    const int q0 = blockIdx.x * 32;
    const int h = blockIdx.y, n = blockIdx.z;
    const int tid = threadIdx.x;
    const int w = tid >> 6, l = tid & 63;
    const int wr = w >> 1, wc = w & 1;
    const int l15 = l & 15, l16 = l >> 4;
    const int qw = q0 + 16 * wr;

    __shared__ alignas(16) ushort Wt[4][16 * ST];
    __shared__ alignas(16) ushort zpL[4][16 * ZST];
    __shared__ alignas(16) ushort zrL[4][16 * ZST];
    __shared__ float mL[4][16], lL[4][16];

    const size_t hb = ((size_t)(n * NHEADS + h)) * SEQLEN * HD;

    bf16x8 qa[2];
    {
        const ushort* qp = Qh + hb + (size_t)(qw + l15) * HD + l16 * 8;
        qa[0] = *(const bf16x8*)(qp);
        qa[1] = *(const bf16x8*)(qp + 32);
    }

    f32x4 zp[4], zr[4];
    #pragma unroll
    for (int nb = 0; nb < 4; ++nb) {
        zp[nb] = (f32x4){0.f, 0.f, 0.f, 0.f};
        zr[nb] = (f32x4){0.f, 0.f, 0.f, 0.f};
    }
    float mrow[4], lrow[4];
    #pragma unroll
    for (int r = 0; r < 4; ++r) { mrow[r] = NEGS; lrow[r] = 0.f; }

    for (int t = wc; t < 32; t += 2) {
        const int c0 = t * 64;
        const bool hasR = (c0 <= q0);
        const bool hasP = (c0 + 63 > qw);

        if (hasP) {
            // ---- QK^T (kb scoped: dead after this block) ----
            f32x4 sc[4];
            #pragma unroll
            for (int nb = 0; nb < 4; ++nb) sc[nb] = (f32x4){0.f, 0.f, 0.f, 0.f};
            {
                #pragma unroll
                for (int ks = 0; ks < 2; ++ks)
                    #pragma unroll
                    for (int nb = 0; nb < 4; ++nb) {
                        bf16x8 kb = *(const bf16x8*)(Kh + hb + (size_t)(c0 + nb * 16 + l15) * HD + ks * 32 + l16 * 8);
                        sc[nb] = __builtin_amdgcn_mfma_f32_16x16x32_bf16(qa[ks], kb, sc[nb], 0, 0, 0);
                    }
            }
            // ---- softmax ----
            float sv[4][4], mt[4], frs[4];
            #pragma unroll
            for (int r = 0; r < 4; ++r) mt[r] = NEGS;
            #pragma unroll
            for (int nb = 0; nb < 4; ++nb)
                #pragma unroll
                for (int r = 0; r < 4; ++r) {
                    float s = sc[nb][r] * SCALE;
                    if (hasR && (c0 + nb * 16 + l15 <= qw + l16 * 4 + r)) s = NEGS;
                    sv[nb][r] = s;
                    mt[r] = fmaxf(mt[r], s);
                }
            #pragma unroll
            for (int r = 0; r < 4; ++r) {
                #pragma unroll
                for (int off = 1; off < 16; off <<= 1)
                    mt[r] = fmaxf(mt[r], __shfl_xor(mt[r], off, 64));
                const float mn = fmaxf(mrow[r], mt[r]);
                frs[r] = __expf(mrow[r] - mn);
                mrow[r] = mn;
                lrow[r] *= frs[r];
            }
            float se[4] = {0.f, 0.f, 0.f, 0.f};
            #pragma unroll
            for (int nb = 0; nb < 4; ++nb)
                #pragma unroll
                for (int r = 0; r < 4; ++r) {
                    const float e = __expf(sv[nb][r] - mrow[r]);
                    se[r] += e;
                    Wt[w][(l16 * 4 + r) * ST + nb * 16 + l15] = f2b(e);
                }
            #pragma unroll
            for (int r = 0; r < 4; ++r) {
                #pragma unroll
                for (int off = 1; off < 16; off <<= 1)
                    se[r] += __shfl_xor(se[r], off, 64);
                lrow[r] += se[r];
            }
            #pragma unroll
            for (int nb = 0; nb < 4; ++nb)
                #pragma unroll
                for (int r = 0; r < 4; ++r) zp[nb][r] *= frs[r];
            // ---- PV (vb loaded here, after softmax: short liveness) ----
            #pragma unroll
            for (int ks = 0; ks < 2; ++ks) {
                bf16x8 wa = *(const bf16x8*)&Wt[w][l15 * ST + ks * 32 + l16 * 8];
                #pragma unroll
                for (int nb = 0; nb < 4; ++nb) {
                    bf16x8 vb = *(const bf16x8*)(VT + hb + (size_t)(nb * 16 + l15) * SEQLEN + c0 + ks * 32 + l16 * 8);
                    zp[nb] = __builtin_amdgcn_mfma_f32_16x16x32_bf16(wa, vb, zp[nb], 0, 0, 0);
                }
            }
        }

        if (hasR) {
            // ---- Q·E^T (skewed) ----
            const int jminW = SEQLEN - 16 - qw + c0;
            f32x4 qe[5];
            #pragma unroll
            for (int jb = 0; jb < 5; ++jb) qe[jb] = (f32x4){0.f, 0.f, 0.f, 0.f};
            #pragma unroll
            for (int ks = 0; ks < 2; ++ks)
                #pragma unroll
                for (int jb = 0; jb < 5; ++jb) {
                    const int j = jminW + jb * 16 + l15;
                    bf16x8 eb;
                    if (j < SEQLEN) eb = *(const bf16x8*)(Eb + (size_t)j * HD + ks * 32 + l16 * 8);
                    else            eb = (bf16x8){0, 0, 0, 0, 0, 0, 0, 0};
                    qe[jb] = __builtin_amdgcn_mfma_f32_16x16x32_bf16(qa[ks], eb, qe[jb], 0, 0, 0);
                }
            // scatter skewed: (rowloc, jl) -> cloc = jl + rowloc - 15
            #pragma unroll
            for (int jb = 0; jb < 5; ++jb)
                #pragma unroll
                for (int r = 0; r < 4; ++r) {
                    const int rowloc = l16 * 4 + r;
                    const int cloc = jb * 16 + l15 + rowloc - 15;
                    if (cloc >= 0 && cloc < 64) {
                        const bool msk = (c0 + cloc <= qw + rowloc);
                        Wt[w][rowloc * ST + cloc] = f2b(msk ? qe[jb][r] : 0.f);
                    }
                }
            #pragma unroll
            for (int ks = 0; ks < 2; ++ks) {
                bf16x8 wa = *(const bf16x8*)&Wt[w][l15 * ST + ks * 32 + l16 * 8];
                #pragma unroll
                for (int nb = 0; nb < 4; ++nb) {
                    bf16x8 vb = *(const bf16x8*)(VT + hb + (size_t)(nb * 16 + l15) * SEQLEN + c0 + ks * 32 + l16 * 8);
                    zr[nb] = __builtin_amdgcn_mfma_f32_16x16x32_bf16(wa, vb, zr[nb], 0, 0, 0);
                }
            }
        }
    }

    // ---------- partial writeout ----------
    #pragma unroll
    for (int nb = 0; nb < 4; ++nb)
        #pragma unroll
        for (int r = 0; r < 4; ++r) {
            const int row = l16 * 4 + r;
            zpL[w][row * ZST + nb * 16 + l15] = f2b(zp[nb][r]);
            zrL[w][row * ZST + nb * 16 + l15] = f2b(zr[nb][r]);
        }
    if (l15 == 0) {
        #pragma unroll
        for (int r = 0; r < 4; ++r) {
            mL[w][l16 * 4 + r] = mrow[r];
            lL[w][l16 * 4 + r] = lrow[r];
        }
    }
    __syncthreads();

    // ---------- merge the two c-parity partials per row-group ----------
    const int d = tid & 63, g = tid >> 6;
    #pragma unroll
    for (int i = 0; i < 8; ++i) {
        const int row = g * 8 + i;                  // 0..31
        const int wr2 = row >> 4, ri = row & 15;
        const int w0 = wr2 * 2, w1 = w0 + 1;
        const float m0 = mL[w0][ri], m1 = mL[w1][ri];
        const float M = fmaxf(m0, m1);
        const float e0 = __expf(m0 - M), e1 = __expf(m1 - M);
        const float L = lL[w0][ri] * e0 + lL[w1][ri] * e1;
        const float zps = b2f(zpL[w0][ri * ZST + d]) * e0 + b2f(zpL[w1][ri * ZST + d]) * e1;
        const float zrs = b2f(zrL[w0][ri * ZST + d]) + b2f(zrL[w1][ri * ZST + d]);
        float z = zps / L + zrs;
        if (q0 + row == SEQLEN - 1)
            z = vsumG[(n * NHEADS + h) * HD + d] * (1.f / (float)SEQLEN) + zrs;
        Z[((size_t)(n * SEQLEN + q0 + row)) * EMB + h * HD + d] = f2b(z);
    }
}

// ---------------- Kernel 3: output projection via MFMA ----------------
__global__ __launch_bounds__(256, 4) void oproj_mfma(
    const ushort* __restrict__ Zb, const ushort* __restrict__ Wob,
    const float* __restrict__ bo, float* __restrict__ out)
{
    __shared__ alignas(16) ushort At[64 * ST];
    __shared__ alignas(16) ushort Bt[64 * ST];
    const int tid = threadIdx.x;
    const int w = tid >> 6, l = tid & 63;
    const int l15 = l & 15, l16 = l >> 4;
    const int m0 = blockIdx.x * 64;
    const int n0 = blockIdx.y * 64;
    const int wm = (w >> 1) * 32, wn = (w & 1) * 32;
    const int r8 = tid >> 3, ch8 = (tid & 7) * 8;

    f32x4 acc[2][2];
    #pragma unroll
    for (int i = 0; i < 2; ++i)
        #pragma unroll
        for (int j = 0; j < 2; ++j) acc[i][j] = (f32x4){0.f, 0.f, 0.f, 0.f};

    for (int kt = 0; kt < 8; ++kt) {
        const int k0 = kt * 64;
        __syncthreads();
        {
            uint4 a0 = *(const uint4*)(Zb  + (size_t)(m0 + r8) * EMB + k0 + ch8);
            uint4 a1 = *(const uint4*)(Zb  + (size_t)(m0 + r8 + 32) * EMB + k0 + ch8);
            uint4 b0 = *(const uint4*)(Wob + (size_t)(n0 + r8) * EMB + k0 + ch8);
            uint4 b1 = *(const uint4*)(Wob + (size_t)(n0 + r8 + 32) * EMB + k0 + ch8);
            *(uint4*)&At[r8 * ST + ch8] = a0;
            *(uint4*)&At[(r8 + 32) * ST + ch8] = a1;
            *(uint4*)&Bt[r8 * ST + ch8] = b0;
            *(uint4*)&Bt[(r8 + 32) * ST + ch8] = b1;
        }
        __syncthreads();
        #pragma unroll
        for (int ks = 0; ks < 2; ++ks) {
            const int ko = ks * 32 + l16 * 8;
            bf16x8 af[2], bf[2];
            #pragma unroll
            for (int i = 0; i < 2; ++i) {
                af[i] = *(const bf16x8*)&At[(wm + i * 16 + l15) * ST + ko];
                bf[i] = *(const bf16x8*)&Bt[(wn + i * 16 + l15) * ST + ko];
            }
            #pragma unroll
            for (int i = 0; i < 2; ++i)
                #pragma unroll
                for (int j = 0; j < 2; ++j)
                    acc[i][j] = __builtin_amdgcn_mfma_f32_16x16x32_bf16(af[i], bf[j], acc[i][j], 0, 0, 0);
        }
    }

    #pragma unroll
    for (int i = 0; i < 2; ++i)
        #pragma unroll
        for (int j = 0; j < 2; ++j) {
            const int o = n0 + wn + j * 16 + l15;
            const float bb = bo[o];
            #pragma unroll
            for (int r = 0; r < 4; ++r) {
                const int t = m0 + wm + i * 16 + l16 * 4 + r;
                out[(size_t)t * EMB + o] = acc[i][j][r] + bb;
            }
        }
}

extern "C" void kernel_launch(void* const* d_in, const int* in_sizes, int n_in,
                              void* d_out, int out_size, void* d_ws, size_t ws_size,
                              hipStream_t stream) {
    const float* v  = (const float*)d_in[0];
    const float* k  = (const float*)d_in[1];
    const float* q  = (const float*)d_in[2];
    const float* Wv = (const float*)d_in[3];
    const float* bv = (const float*)d_in[4];
    const float* Wk = (const float*)d_in[5];
    const float* bk = (const float*)d_in[6];
    const float* Wq = (const float*)d_in[7];
    const float* bq = (const float*)d_in[8];
    const float* E  = (const float*)d_in[9];
    const float* Wo = (const float*)d_in[10];
    const float* bo = (const float*)d_in[11];
    float* out = (float*)d_out;

    ushort* wsu = (ushort*)d_ws;
    const size_t perE = (size_t)NB * NHEADS * SEQLEN * HD;     // 2,097,152
    ushort* Qh  = wsu;
    ushort* Kh  = wsu + perE;
    ushort* VT  = wsu + 2 * perE;
    ushort* Eb  = wsu + 3 * perE;                              // 131072
    ushort* Wob = wsu + 3 * perE + 131072;                     // 262144
    ushort* Zb  = wsu + 3 * perE + 131072 + 262144;            // 2,097,152
    float*  vsumG = (float*)(Zb + perE);                       // 1024 f32

    dim3 gp(NB * SEQLEN / 64, NHEADS, 3);
    proj_mfma<<<gp, 256, 0, stream>>>(q, k, v, Wq, bq, Wk, bk, Wv, bv, Qh, Kh, VT);

    econv2_kernel<<<(SEQLEN * HD + EMB * EMB) / (256 * 4), 256, 0, stream>>>(E, Eb, Wo, Wob);

    vsum_kernel<<<NB * NHEADS, 256, 0, stream>>>(VT, vsumG);

    dim3 g2(SEQLEN / 32, NHEADS, NB);
    attn_mfma<<<g2, 256, 0, stream>>>(Qh, Kh, VT, Eb, vsumG, Zb);

    dim3 g3(NB * SEQLEN / 64, EMB / 64);
    oproj_mfma<<<g3, 256, 0, stream>>>(Zb, Wob, bo, out);
}